// Round 1
// baseline (353.828 us; speedup 1.0000x reference)
//
#include <hip/hip_runtime.h>
#include <math.h>

#define MASK_SIZE 28
#define MASK_PIX (MASK_SIZE * MASK_SIZE)
// Shapes fixed by reference setup_inputs(): P=512, G=200, H=520, W=704.
#define GT_H 520
#define GT_W 704

// ws layout: wsf[0] = loss sum (float); wsi[1] = num_pos (int); wsi[2..2+P) = matched gt idx (or -1)

__global__ void iou_kernel(const float* __restrict__ proposals,
                           const float* __restrict__ gt_boxes,
                           int P, int G,
                           float* __restrict__ wssum,
                           int* __restrict__ wsnpos,
                           int* __restrict__ wsmidx) {
    extern __shared__ float sb[];  // G*4 floats of gt boxes
    int tid = threadIdx.x;
    for (int i = tid; i < G * 4; i += blockDim.x) sb[i] = gt_boxes[i];
    __shared__ int s_npos;
    if (tid == 0) s_npos = 0;
    __syncthreads();

    int pos = 0;
    if (tid < P) {
        float ax1 = proposals[tid * 4 + 0], ay1 = proposals[tid * 4 + 1];
        float ax2 = proposals[tid * 4 + 2], ay2 = proposals[tid * 4 + 3];
        float area_a = (ax2 - ax1) * (ay2 - ay1);
        float best = -1.0f;
        int bidx = 0;
        for (int j = 0; j < G; ++j) {
            float bx1 = sb[j * 4 + 0], by1 = sb[j * 4 + 1];
            float bx2 = sb[j * 4 + 2], by2 = sb[j * 4 + 3];
            float area_b = (bx2 - bx1) * (by2 - by1);
            float lx = fmaxf(ax1, bx1), ly = fmaxf(ay1, by1);
            float rx = fminf(ax2, bx2), ry = fminf(ay2, by2);
            float w = fmaxf(rx - lx, 0.0f), h = fmaxf(ry - ly, 0.0f);
            float inter = w * h;
            float iou = inter / (area_a + area_b - inter);
            if (iou > best) { best = iou; bidx = j; }  // strict > == jnp first-occurrence argmax
        }
        pos = (best > 0.3f) ? 1 : 0;
        wsmidx[tid] = pos ? bidx : -1;
    }
    unsigned long long m = __ballot(pos);
    if ((tid & 63) == 0) atomicAdd(&s_npos, __popcll(m));
    __syncthreads();
    if (tid == 0) {
        *wssum = 0.0f;   // ws is poisoned 0xAA every launch — must init here
        *wsnpos = s_npos;
    }
}

__global__ void bce_kernel(const float* __restrict__ mask_logits,
                           const float* __restrict__ gt_boxes,
                           const float* __restrict__ gt_masks,
                           const int* __restrict__ wsmidx,
                           float* __restrict__ wssum,
                           int H, int W) {
    int p = blockIdx.x;
    int g = wsmidx[p];
    if (g < 0) return;  // block-uniform early exit for non-positive proposals

    float bx1f = gt_boxes[g * 4 + 0], by1f = gt_boxes[g * 4 + 1];
    float bx2f = gt_boxes[g * 4 + 2], by2f = gt_boxes[g * 4 + 3];
    int b0 = (int)bx1f, b1 = (int)by1f, b2 = (int)bx2f, b3 = (int)by2f;
    int x1 = min(max(b0, 0), W - 1);
    int y1 = min(max(b1, 0), H - 1);
    int x2 = max(x1 + 1, min(b2, W));
    int y2 = max(y1 + 1, min(b3, H));
    float cw = (float)(x2 - x1), ch = (float)(y2 - y1);
    const float* mrow = gt_masks + (size_t)g * H * W;

    float lsum = 0.0f;
    for (int i = threadIdx.x; i < MASK_PIX; i += blockDim.x) {
        int py = i / MASK_SIZE, px = i % MASK_SIZE;
        float sy = fminf(fmaxf(((float)py + 0.5f) * ch / (float)MASK_SIZE - 0.5f, 0.0f), ch - 1.0f);
        float sx = fminf(fmaxf(((float)px + 0.5f) * cw / (float)MASK_SIZE - 0.5f, 0.0f), cw - 1.0f);
        int y0 = (int)floorf(sy);
        int x0 = (int)floorf(sx);
        int yp = min(y0 + 1, (y2 - y1) - 1);
        int xp = min(x0 + 1, (x2 - x1) - 1);
        float wy = sy - (float)y0;
        float wx = sx - (float)x0;
        int Y0 = y1 + y0, Y1 = y1 + yp, X0 = x1 + x0, X1 = x1 + xp;
        float t00 = mrow[Y0 * W + X0];
        float t01 = mrow[Y0 * W + X1];
        float t10 = mrow[Y1 * W + X0];
        float t11 = mrow[Y1 * W + X1];
        float tgt = (1.0f - wy) * (1.0f - wx) * t00 + (1.0f - wy) * wx * t01
                  + wy * (1.0f - wx) * t10 + wy * wx * t11;
        float l = mask_logits[((size_t)p * 2 + 1) * MASK_PIX + i];
        // jax.nn.softplus stable form: max(x,0) + log1p(exp(-|x|))
        float bce = fmaxf(l, 0.0f) + log1pf(expf(-fabsf(l))) - l * tgt;
        lsum += bce;
    }

    // wave-64 shuffle reduce, then cross-wave via LDS
    for (int off = 32; off > 0; off >>= 1) lsum += __shfl_down(lsum, off, 64);
    __shared__ float swave[16];
    int wid = threadIdx.x >> 6;
    if ((threadIdx.x & 63) == 0) swave[wid] = lsum;
    __syncthreads();
    if (threadIdx.x == 0) {
        float tot = 0.0f;
        int nw = blockDim.x >> 6;
        for (int w = 0; w < nw; ++w) tot += swave[w];
        atomicAdd(wssum, tot);
    }
}

__global__ void finalize_kernel(const float* __restrict__ wssum,
                                const int* __restrict__ wsnpos,
                                float* __restrict__ out) {
    float s = *wssum;
    int np = *wsnpos;
    float denom = fmaxf((float)np, 1.0f) * (float)MASK_PIX;
    out[0] = (np > 0) ? (s / denom) : 0.0f;
}

extern "C" void kernel_launch(void* const* d_in, const int* in_sizes, int n_in,
                              void* d_out, int out_size, void* d_ws, size_t ws_size,
                              hipStream_t stream) {
    const float* mask_logits = (const float*)d_in[0];  // (P,2,28,28) f32
    const float* proposals   = (const float*)d_in[1];  // (P,4) f32
    const float* gt_boxes    = (const float*)d_in[2];  // (G,4) f32
    const float* gt_masks    = (const float*)d_in[3];  // (G,H,W) f32
    // d_in[4] = gt_labels (unused by reference math)
    float* out = (float*)d_out;

    int P = in_sizes[1] / 4;
    int G = in_sizes[2] / 4;

    float* wsf = (float*)d_ws;
    int* wsi = (int*)d_ws;
    float* wssum = &wsf[0];
    int* wsnpos = &wsi[1];
    int* wsmidx = &wsi[2];

    iou_kernel<<<1, P, G * 4 * sizeof(float), stream>>>(proposals, gt_boxes, P, G,
                                                        wssum, wsnpos, wsmidx);
    bce_kernel<<<P, 256, 0, stream>>>(mask_logits, gt_boxes, gt_masks, wsmidx, wssum,
                                      GT_H, GT_W);
    finalize_kernel<<<1, 1, 0, stream>>>(wssum, wsnpos, out);
}